// Round 2
// baseline (580.406 us; speedup 1.0000x reference)
//
#include <hip/hip_runtime.h>

#define N_NODES 131072
#define MAXL 4096

// ws float offsets
#define OFF_QW     0u          // 64*256   folded (Q@WK)/16
#define OFF_QO     16384u      // 64*256   Q@WO^T
#define OFF_WF     32768u      // 256*256  WO@WV
#define OFF_QB     98304u      // 64
#define OFF_BVO    98368u      // 256
#define OFF_STARTS 98624u      // 65 ints
#define OFF_ASUM   98752u      // 64*64
#define OFF_A      102912u     // 131072*64 (Q reuses the head of this transiently)
#define OFF_G      8491520u    // partial G slabs (or single G in atomic mode)

// ---------------- setup kernels ----------------

__global__ __launch_bounds__(256) void k_q(const float* __restrict__ Qp,
    const float* __restrict__ WQ_w, const float* __restrict__ WQ_b,
    float* __restrict__ Q)
{
  const int c = blockIdx.x, d = threadIdx.x;
  float acc = WQ_b[d];
  #pragma unroll 4
  for (int k = 0; k < 256; k += 4) {
    float4 w = *(const float4*)&WQ_w[d * 256 + k];
    acc += Qp[c * 256 + k + 0] * w.x + Qp[c * 256 + k + 1] * w.y
         + Qp[c * 256 + k + 2] * w.z + Qp[c * 256 + k + 3] * w.w;
  }
  Q[c * 256 + d] = acc;
}

__global__ __launch_bounds__(256) void k_fold(const float* __restrict__ Q,
    const float* __restrict__ WK_w, const float* __restrict__ WK_b,
    const float* __restrict__ WO_w,
    float* __restrict__ QW, float* __restrict__ QO, float* __restrict__ qb)
{
  const int c = blockIdx.x, d = threadIdx.x;
  double aqw = 0.0;
  float aqo = 0.f;
  for (int j = 0; j < 256; ++j) {
    float qcj = Q[c * 256 + j];
    aqw += (double)qcj * (double)WK_w[j * 256 + d];   // coalesced over d
    aqo += qcj * WO_w[d * 256 + j];
  }
  QW[c * 256 + d] = (float)(aqw * 0.0625);  // 1/sqrt(256)
  QO[c * 256 + d] = aqo;
  if (d == 0) {
    double s = 0.0;
    for (int j = 0; j < 256; ++j) s += (double)Q[c * 256 + j] * (double)WK_b[j];
    qb[c] = (float)(s * 0.0625);
  }
}

__global__ __launch_bounds__(256) void k_wf(const float* __restrict__ WO_w,
    const float* __restrict__ WV_w, const float* __restrict__ WV_b,
    float* __restrict__ Wf, float* __restrict__ bvo)
{
  const int i = blockIdx.x, d = threadIdx.x;
  float acc = 0.f;
  for (int j = 0; j < 256; ++j)
    acc += WO_w[i * 256 + j] * WV_w[j * 256 + d];   // coalesced over d
  Wf[i * 256 + d] = acc;
  if (d == 0) {
    float s = 0.f;
    for (int j = 0; j < 256; ++j) s += WV_b[j] * WO_w[i * 256 + j];
    bvo[i] = s;
  }
}

__global__ void k_starts(const int* __restrict__ batch, int* __restrict__ starts)
{
  int t = threadIdx.x;
  if (t > 64) return;
  if (t == 0) { starts[0] = 0; return; }
  if (t == 64) { starts[64] = N_NODES; return; }
  int lo = 0, hi = N_NODES;
  while (lo < hi) {
    int mid = (lo + hi) >> 1;
    if (batch[mid] < t) lo = mid + 1; else hi = mid;
  }
  starts[t] = lo;
}

// ---------------- pass 1: node-per-thread scores + softmax + argmax + mask ----
// 64-thread blocks (1 wave), 64 nodes/block. qw is block-uniform -> s_load
// operands; only x goes through LDS. acc[64] lives in VGPRs.

__global__ __launch_bounds__(64, 4) void k_scores(
    const float* __restrict__ x, const int* __restrict__ batch,
    const float* __restrict__ qw, const float* __restrict__ qbv,
    const int* __restrict__ starts, float* __restrict__ A,
    float* __restrict__ out_arg, float* __restrict__ out_msk)
{
  __shared__ float xs[64 * 36];    // 64 rows x 32 floats, pad to 36 (9 quads)
  const int t = threadIdx.x;
  const int n0 = blockIdx.x * 64;

  float acc[64];
  #pragma unroll
  for (int c = 0; c < 64; ++c) acc[c] = 0.f;

  #pragma unroll 1
  for (int kc = 0; kc < 8; ++kc) {
    const int k0 = kc * 32;
    // stage x[n0..n0+64) [k0..k0+32) -- coalesced 128B per 8 lanes
    #pragma unroll
    for (int u = 0; u < 8; ++u) {
      int v = t + 64 * u;
      int row = v >> 3, col = v & 7;
      *(float4*)&xs[row * 36 + col * 4] =
          *(const float4*)&x[(size_t)(n0 + row) * 256 + k0 + col * 4];
    }
    __syncthreads();
    #pragma unroll 1
    for (int h = 0; h < 2; ++h) {
      float4 xv0 = *(const float4*)&xs[t * 36 + h * 16 + 0];
      float4 xv1 = *(const float4*)&xs[t * 36 + h * 16 + 4];
      float4 xv2 = *(const float4*)&xs[t * 36 + h * 16 + 8];
      float4 xv3 = *(const float4*)&xs[t * 36 + h * 16 + 12];
      const float* qp = qw + k0 + h * 16;     // uniform address -> scalar loads
      #pragma unroll
      for (int c = 0; c < 64; ++c) {
        float4 q0 = *(const float4*)&qp[c * 256 + 0];
        float4 q1 = *(const float4*)&qp[c * 256 + 4];
        float4 q2 = *(const float4*)&qp[c * 256 + 8];
        float4 q3 = *(const float4*)&qp[c * 256 + 12];
        acc[c] += xv0.x * q0.x + xv0.y * q0.y + xv0.z * q0.z + xv0.w * q0.w
                + xv1.x * q1.x + xv1.y * q1.y + xv1.z * q1.z + xv1.w * q1.w
                + xv2.x * q2.x + xv2.y * q2.y + xv2.z * q2.z + xv2.w * q2.w
                + xv3.x * q3.x + xv3.y * q3.y + xv3.z * q3.z + xv3.w * q3.w;
      }
    }
    __syncthreads();
  }

  // epilogue: bias, argmax, softmax over c -- all in registers
  #pragma unroll
  for (int c = 0; c < 64; ++c) acc[c] += qbv[c];
  float m = acc[0]; int am = 0;
  #pragma unroll
  for (int c = 1; c < 64; ++c)
    if (acc[c] > m) { m = acc[c]; am = c; }   // strict > : first-max, matches np
  float sum = 0.f;
  #pragma unroll
  for (int c = 0; c < 64; ++c) { acc[c] = __expf(acc[c] - m); sum += acc[c]; }
  float inv = 1.f / sum;

  const int n = n0 + t;
  #pragma unroll
  for (int c4 = 0; c4 < 16; ++c4) {
    float4 v = make_float4(acc[c4 * 4 + 0] * inv, acc[c4 * 4 + 1] * inv,
                           acc[c4 * 4 + 2] * inv, acc[c4 * 4 + 3] * inv);
    *(float4*)&A[(size_t)n * 64 + c4 * 4] = v;
  }
  int bg = batch[n];
  int pos = n - starts[bg];
  out_arg[(size_t)bg * MAXL + pos] = (float)am;
  out_msk[(size_t)bg * MAXL + pos] = 1.0f;
}

// ---------------- pass 2: G[b] = A_b^T X_b (8x8 register tile) ---------------
// grid (nchunk, 64 graphs). Partial mode: each block stores its own G slab;
// atomic mode (small ws): atomicAdd into single G.

__global__ __launch_bounds__(256) void k_gacc(
    const float* __restrict__ x, const float* __restrict__ A,
    const int* __restrict__ starts, float* __restrict__ Gdst,
    float* __restrict__ asum, int use_atomic)
{
  __shared__ float as_[32 * 68];    // [n][c] pad 64->68
  __shared__ float xs[32 * 260];    // [n][d] pad 256->260
  const int t = threadIdx.x;
  const int b = blockIdx.y;
  const int s0 = starts[b], s1 = starts[b + 1];
  const int cg = t & 7, dg = t >> 3;   // c = cg*8+i, d = dg*8+j

  float acc[8][8];
  #pragma unroll
  for (int i = 0; i < 8; ++i)
    #pragma unroll
    for (int j = 0; j < 8; ++j) acc[i][j] = 0.f;
  float asv = 0.f;

  const int stride = gridDim.x * 32;
  for (int base = s0 + blockIdx.x * 32; base < s1; base += stride) {
    #pragma unroll
    for (int u = 0; u < 2; ++u) {
      int v = t + 256 * u;
      int row = v >> 4, col = v & 15;
      int gr = base + row;
      float4 av = make_float4(0.f, 0.f, 0.f, 0.f);
      if (gr < s1) av = *(const float4*)&A[(size_t)gr * 64 + col * 4];
      *(float4*)&as_[row * 68 + col * 4] = av;     // zero rows: no contribution
    }
    #pragma unroll
    for (int u = 0; u < 8; ++u) {
      int v = t + 256 * u;
      int row = v >> 6, col = v & 63;
      int gr = base + row; if (gr >= s1) gr = s1 - 1;   // stay in-bounds; a=0
      *(float4*)&xs[row * 260 + col * 4] =
          *(const float4*)&x[(size_t)gr * 256 + col * 4];
    }
    __syncthreads();
    #pragma unroll 4
    for (int r = 0; r < 32; ++r) {
      float4 a0 = *(const float4*)&as_[r * 68 + cg * 8];
      float4 a1 = *(const float4*)&as_[r * 68 + cg * 8 + 4];
      float4 x0 = *(const float4*)&xs[r * 260 + dg * 8];
      float4 x1 = *(const float4*)&xs[r * 260 + dg * 8 + 4];
      float ar[8] = {a0.x, a0.y, a0.z, a0.w, a1.x, a1.y, a1.z, a1.w};
      float xr[8] = {x0.x, x0.y, x0.z, x0.w, x1.x, x1.y, x1.z, x1.w};
      #pragma unroll
      for (int i = 0; i < 8; ++i)
        #pragma unroll
        for (int j = 0; j < 8; ++j) acc[i][j] += ar[i] * xr[j];
    }
    if (t < 64) {                      // asum column-sum (graph-exact, cheap)
      #pragma unroll 8
      for (int r = 0; r < 32; ++r) asv += as_[r * 68 + t];
    }
    __syncthreads();
  }

  if (use_atomic) {
    float* g = Gdst + (size_t)b * 16384;
    #pragma unroll
    for (int i = 0; i < 8; ++i)
      #pragma unroll
      for (int j = 0; j < 8; ++j)
        atomicAdd(&g[(cg * 8 + i) * 256 + dg * 8 + j], acc[i][j]);
  } else {
    float* g = Gdst + ((size_t)blockIdx.x * 64 + b) * 16384;
    #pragma unroll
    for (int i = 0; i < 8; ++i) {
      *(float4*)&g[(cg * 8 + i) * 256 + dg * 8] =
          make_float4(acc[i][0], acc[i][1], acc[i][2], acc[i][3]);
      *(float4*)&g[(cg * 8 + i) * 256 + dg * 8 + 4] =
          make_float4(acc[i][4], acc[i][5], acc[i][6], acc[i][7]);
    }
  }
  if (t < 64) atomicAdd(&asum[b * 64 + t], asv);
}

// ---------------- finalize: out = relu(qo + (sum_p Gp)@Wf^T + asum*bvo + b) --

__global__ __launch_bounds__(256) void k_final(const float* __restrict__ Gp,
    int npart, const float* __restrict__ Wf, const float* __restrict__ qo,
    const float* __restrict__ asum, const float* __restrict__ bvo,
    const float* __restrict__ WO_b, float* __restrict__ out)
{
  __shared__ float gs[64 * 68];
  __shared__ float wfs[64 * 68];
  const int t = threadIdx.x;
  const int b = blockIdx.x >> 2;
  const int is = (blockIdx.x & 3) * 64;
  const int tx = t & 15, ty = t >> 4;   // c = ty+16j, i = is + tx+16u
  const int sr = t >> 4, sq = t & 15;

  float acc[4][4];
  #pragma unroll
  for (int j = 0; j < 4; ++j)
    #pragma unroll
    for (int u = 0; u < 4; ++u) acc[j][u] = 0.f;

  for (int kc = 0; kc < 4; ++kc) {
    const int k0 = kc * 64;
    #pragma unroll
    for (int u = 0; u < 4; ++u) {
      int row = sr + 16 * u;
      float4 g = make_float4(0.f, 0.f, 0.f, 0.f);
      for (int p = 0; p < npart; ++p) {
        float4 gv = *(const float4*)&Gp[((size_t)p * 64 + b) * 16384
                                        + row * 256 + k0 + sq * 4];
        g.x += gv.x; g.y += gv.y; g.z += gv.z; g.w += gv.w;
      }
      *(float4*)&gs[row * 68 + sq * 4] = g;
      *(float4*)&wfs[row * 68 + sq * 4] =
          *(const float4*)&Wf[(size_t)(is + row) * 256 + k0 + sq * 4];
    }
    __syncthreads();
    #pragma unroll
    for (int k4 = 0; k4 < 16; ++k4) {
      float4 gr[4], wr[4];
      #pragma unroll
      for (int j = 0; j < 4; ++j) gr[j] = *(const float4*)&gs[(ty + 16 * j) * 68 + k4 * 4];
      #pragma unroll
      for (int u = 0; u < 4; ++u) wr[u] = *(const float4*)&wfs[(tx + 16 * u) * 68 + k4 * 4];
      #pragma unroll
      for (int j = 0; j < 4; ++j)
        #pragma unroll
        for (int u = 0; u < 4; ++u)
          acc[j][u] += gr[j].x * wr[u].x + gr[j].y * wr[u].y
                     + gr[j].z * wr[u].z + gr[j].w * wr[u].w;
    }
    __syncthreads();
  }

  #pragma unroll
  for (int j = 0; j < 4; ++j)
    #pragma unroll
    for (int u = 0; u < 4; ++u) {
      int c = ty + 16 * j, i = is + tx + 16 * u;
      float v = acc[j][u] + qo[c * 256 + i] + asum[b * 64 + c] * bvo[i] + WO_b[i];
      out[(size_t)b * 16384 + c * 256 + i] = fmaxf(v, 0.f);
    }
}

// ---------------- launch ----------------

extern "C" void kernel_launch(void* const* d_in, const int* in_sizes, int n_in,
                              void* d_out, int out_size, void* d_ws, size_t ws_size,
                              hipStream_t stream) {
  const float* x    = (const float*)d_in[0];
  const int*   batch= (const int*)d_in[1];
  const float* Qp   = (const float*)d_in[2];
  const float* WQ_w = (const float*)d_in[3];
  const float* WQ_b = (const float*)d_in[4];
  const float* WK_w = (const float*)d_in[5];
  const float* WK_b = (const float*)d_in[6];
  const float* WV_w = (const float*)d_in[7];
  const float* WV_b = (const float*)d_in[8];
  const float* WO_w = (const float*)d_in[9];
  const float* WO_b = (const float*)d_in[10];

  float* ws   = (float*)d_ws;
  float* QW   = ws + OFF_QW;
  float* QO   = ws + OFF_QO;
  float* Wf   = ws + OFF_WF;
  float* qb   = ws + OFF_QB;
  float* bvo  = ws + OFF_BVO;
  int*   starts = (int*)(ws + OFF_STARTS);
  float* asum = ws + OFF_ASUM;
  float* A    = ws + OFF_A;
  float* Q    = ws + OFF_A;   // transient reuse: k_fold consumes Q before A is written
  float* Gp   = ws + OFF_G;

  float* out     = (float*)d_out;                 // [64][64][256]
  float* out_arg = out + 64 * 64 * 256;           // [64][4096]
  float* out_msk = out_arg + 64 * MAXL;           // [64][4096]

  // G partial slabs if ws permits; else proven-fit atomic single-slab path
  size_t ws_f = ws_size / 4;
  size_t avail = ws_f > OFF_G ? ws_f - OFF_G : 0;
  size_t cap = avail / (64 * 16384);
  int npart, use_atomic;
  if (cap >= 4) { npart = (int)(cap < 16 ? cap : 16); use_atomic = 0; }
  else         { npart = 1; use_atomic = 1; }
  int nchunk = use_atomic ? 16 : npart;

  hipMemsetAsync(asum, 0, 64 * 64 * sizeof(float), stream);
  hipMemsetAsync(out_arg, 0, (size_t)2 * 64 * MAXL * sizeof(float), stream);
  if (use_atomic) hipMemsetAsync(Gp, 0, (size_t)64 * 16384 * sizeof(float), stream);

  k_q<<<64, 256, 0, stream>>>(Qp, WQ_w, WQ_b, Q);
  k_wf<<<256, 256, 0, stream>>>(WO_w, WV_w, WV_b, Wf, bvo);
  k_starts<<<1, 128, 0, stream>>>(batch, starts);
  k_fold<<<64, 256, 0, stream>>>(Q, WK_w, WK_b, WO_w, QW, QO, qb);

  k_scores<<<N_NODES / 64, 64, 0, stream>>>(x, batch, QW, qb, starts,
                                            A, out_arg, out_msk);
  k_gacc<<<dim3(nchunk, 64), 256, 0, stream>>>(x, A, starts, Gp, asum, use_atomic);
  k_final<<<64 * 4, 256, 0, stream>>>(Gp, npart, Wf, QO, asum, bvo, WO_b, out);
}